// Round 9
// baseline (60.435 us; speedup 1.0000x reference)
//
#include <hip/hip_runtime.h>
#include <hip/hip_bf16.h>

#define D_DIM 256
#define K_CODES 1024
#define N_ROWS (32 * 1024)
#define BLOCK_ROWS 64                 // rows per main block (2 rg x 32)
#define NRG (N_ROWS / BLOCK_ROWS)     // 512 row-groups
#define NBLK (NRG * 2)                // x2 code-halves = 1024 main blocks
#define STEPS 16                      // 16-code tiles per kg (256 codes)
#define TILE_SH 4128                  // shorts per tile: 8KB frags + 64B enorm

typedef __attribute__((ext_vector_type(8))) short bf16x8;
typedef __attribute__((ext_vector_type(4))) float f32x4;

#define MFMA16 __builtin_amdgcn_mfma_f32_16x16x32_bf16

static __device__ __forceinline__ short f2bf(float f) {
    __hip_bfloat16 h = __float2bfloat16(f);   // RNE
    return *reinterpret_cast<short*>(&h);
}

static __device__ __forceinline__ bf16x8 pack8(float4 a, float4 b) {
    bf16x8 r;
    r[0] = f2bf(a.x); r[1] = f2bf(a.y); r[2] = f2bf(a.z); r[3] = f2bf(a.w);
    r[4] = f2bf(b.x); r[5] = f2bf(b.y); r[6] = f2bf(b.z); r[7] = f2bf(b.w);
    return r;
}

static __device__ __forceinline__ void gload_lds16(const void* g, void* s) {
    __builtin_amdgcn_global_load_lds(
        (const __attribute__((address_space(1))) void*)g,
        (__attribute__((address_space(3))) void*)s, 16, 0, 0);
}
static __device__ __forceinline__ void gload_lds4(const void* g, void* s) {
    __builtin_amdgcn_global_load_lds(
        (const __attribute__((address_space(1))) void*)g,
        (__attribute__((address_space(3))) void*)s, 4, 0, 0);
}

// ---------------------------------------------------------------- prep
// Fused: (a) enorm[k] = ||E[k]||^2  (one wave per code row)
//        (b) Eb = bf16(-2*E) in MFMA B-fragment order (blocks 0..127)
// frag g = t*512 + kk*64 + l holds E[code = t*16 + (l&15)][d = kk*32 + (l>>4)*8 ..+8]
__global__ __launch_bounds__(256) void vq_prep(const float* __restrict__ E,
                                               float* __restrict__ enorm,
                                               short* __restrict__ Eb) {
    int wave = threadIdx.x >> 6;
    int lane = threadIdx.x & 63;
    int k = blockIdx.x * 4 + wave;               // [0,1024)
    const float4 v = *reinterpret_cast<const float4*>(E + k * D_DIM + lane * 4);
    float s = v.x * v.x + v.y * v.y + v.z * v.z + v.w * v.w;
    #pragma unroll
    for (int off = 32; off; off >>= 1) s += __shfl_xor(s, off, 64);
    if (lane == 0) enorm[k] = s;

    if (blockIdx.x < 128) {
        int g = blockIdx.x * 256 + threadIdx.x;  // [0, 32768)
        int t = g >> 9;
        int kk = (g >> 6) & 7;
        int l = g & 63;
        int code = t * 16 + (l & 15);
        int d = kk * 32 + ((l >> 4) << 3);
        const float* src = E + (size_t)code * D_DIM + d;
        float4 v0 = *reinterpret_cast<const float4*>(src);
        float4 v1 = *reinterpret_cast<const float4*>(src + 4);
        v0.x *= -2.f; v0.y *= -2.f; v0.z *= -2.f; v0.w *= -2.f;
        v1.x *= -2.f; v1.y *= -2.f; v1.z *= -2.f; v1.w *= -2.f;
        *reinterpret_cast<bf16x8*>(Eb + (size_t)g * 8) = pack8(v0, v1);
    }
}

// ---------------------------------------------------------------- main
// bid = rg-group*2 + cy.  Block: 64 rows x 512 codes (code-half cy).
// 4 waves = kg2 x rg2; wave = 32 rows (2 rowsets, A in regs) x 256 codes
// (16 tiles of 16). Triple-buffered LDS tiles, counted vmcnt(5), raw
// s_barrier (R7 machinery, STEPS=16). Block argmin -> global (val,idx)
// partial per (row, code-half); gather/loss moved to vq_gather.
__global__ __launch_bounds__(256, 3) void vq_main(const float* __restrict__ X,
                                                  const float* __restrict__ enorm,
                                                  const short* __restrict__ Eb,
                                                  float2* __restrict__ pairs) {
    __shared__ short lds[2][3][TILE_SH];   // ~49.5 KB
    __shared__ float mv[2][BLOCK_ROWS];
    __shared__ int   mi[2][BLOCK_ROWS];

    const int tid  = threadIdx.x;
    const int wave = tid >> 6;
    const int kg   = wave >> 1;   // code sub-half within block
    const int rg   = wave & 1;    // row half
    const int l    = tid & 63;
    const int lr   = l & 15;      // A row-in-16 / B,C code col
    const int lk   = l >> 4;
    const int cy    = blockIdx.x & 1;            // code half (512 codes)
    const int brow0 = (blockIdx.x >> 1) * BLOCK_ROWS;
    const int row0  = brow0 + rg * 32;
    const int tgb   = cy * 32 + kg * 16;         // first global 16-code tile

    // 5 loads per wave per stage: 4 fragment chunks + enorm slab (dup by rg)
#define STAGE(TT, BUF)                                                        \
    do {                                                                      \
        const int tg_ = tgb + (TT);                                           \
        _Pragma("unroll")                                                     \
        for (int kv = 0; kv < 4; ++kv) {                                      \
            const int kk_ = rg * 4 + kv;                                      \
            gload_lds16(Eb + ((size_t)tg_ * 512 + kk_ * 64 + l) * 8,          \
                        &lds[kg][BUF][kk_ * 512]);                            \
        }                                                                     \
        if (l < 16) gload_lds4(enorm + tg_ * 16 + l, &lds[kg][BUF][4096]);    \
    } while (0)

    STAGE(0, 0);
    STAGE(1, 1);

    // ---- prologue: this wave's 32 rows of X -> bf16 A-fragments
    bf16x8 a[2][8];
    #pragma unroll
    for (int s = 0; s < 2; ++s) {
        const float* xp = X + (size_t)(row0 + s * 16 + lr) * D_DIM + lk * 8;
        #pragma unroll
        for (int kk = 0; kk < 8; ++kk) {
            float4 p = *reinterpret_cast<const float4*>(xp + kk * 32);
            float4 q = *reinterpret_cast<const float4*>(xp + kk * 32 + 4);
            a[s][kk] = pack8(p, q);
        }
    }

    float minv[2][4];
    int   mini[2][4];
    #pragma unroll
    for (int s = 0; s < 2; ++s)
        #pragma unroll
        for (int i = 0; i < 4; ++i) { minv[s][i] = INFINITY; mini[s][i] = 0; }

#define STEP(TT, LAST)                                                        \
    do {                                                                      \
        const int buf_ = (TT) % 3;                                            \
        if (LAST) { asm volatile("s_waitcnt vmcnt(0)" ::: "memory"); }        \
        else      { asm volatile("s_waitcnt vmcnt(5)" ::: "memory"); }        \
        __builtin_amdgcn_sched_barrier(0);                                    \
        __builtin_amdgcn_s_barrier();                                         \
        bf16x8 b[8];                                                          \
        _Pragma("unroll")                                                     \
        for (int kk = 0; kk < 8; ++kk)                                        \
            b[kk] = *reinterpret_cast<const bf16x8*>(                         \
                &lds[kg][buf_][kk * 512 + l * 8]);                            \
        const float en = *reinterpret_cast<const float*>(                     \
            &lds[kg][buf_][4096 + lr * 2]);                                   \
        if (!(LAST) && (TT) + 2 < STEPS) STAGE((TT) + 2, ((TT) + 2) % 3);     \
        f32x4 acc0 = {0, 0, 0, 0}, acc1 = {0, 0, 0, 0};                       \
        _Pragma("unroll")                                                     \
        for (int kk = 0; kk < 8; ++kk) {                                      \
            acc0 = MFMA16(a[0][kk], b[kk], acc0, 0, 0, 0);                    \
            acc1 = MFMA16(a[1][kk], b[kk], acc1, 0, 0, 0);                    \
        }                                                                     \
        const int idx_ = (tgb + (TT)) * 16 + lr;                              \
        _Pragma("unroll")                                                     \
        for (int i = 0; i < 4; ++i) {                                         \
            float s0 = acc0[i] + en;                                          \
            float s1 = acc1[i] + en;                                          \
            if (s0 < minv[0][i]) { minv[0][i] = s0; mini[0][i] = idx_; }      \
            if (s1 < minv[1][i]) { minv[1][i] = s1; mini[1][i] = idx_; }      \
        }                                                                     \
        __builtin_amdgcn_sched_barrier(0);                                    \
    } while (0)

    for (int tt = 0; tt < STEPS - 1; ++tt) STEP(tt, false);
    STEP(STEPS - 1, true);
#undef STEP
#undef STAGE

    // ---- reduce over the 16 code-lanes (first-min tie-break)
    #pragma unroll
    for (int off = 8; off >= 1; off >>= 1) {
        #pragma unroll
        for (int s = 0; s < 2; ++s)
            #pragma unroll
            for (int i = 0; i < 4; ++i) {
                float ov = __shfl_xor(minv[s][i], off, 64);
                int   oi = __shfl_xor(mini[s][i], off, 64);
                if (ov < minv[s][i] || (ov == minv[s][i] && oi < mini[s][i])) {
                    minv[s][i] = ov; mini[s][i] = oi;
                }
            }
    }

    // ---- publish per-wave, merge the 2 kg-groups, write global partial
    if (lr == 0) {
        #pragma unroll
        for (int s = 0; s < 2; ++s)
            #pragma unroll
            for (int i = 0; i < 4; ++i) {
                mv[kg][rg * 32 + s * 16 + lk * 4 + i] = minv[s][i];
                mi[kg][rg * 32 + s * 16 + lk * 4 + i] = mini[s][i];
            }
    }
    __syncthreads();
    if (tid < BLOCK_ROWS) {
        float bv = mv[0][tid]; int bi = mi[0][tid];
        float v  = mv[1][tid]; int ii = mi[1][tid];
        if (v < bv || (v == bv && ii < bi)) { bv = v; bi = ii; }
        float2 p; p.x = bv; p.y = __int_as_float(bi);
        pairs[(size_t)(brow0 + tid) * 2 + cy] = p;
    }
}

// ---------------------------------------------------------------- gather
// Merge the 2 code-half partials per row, gather E[idx] -> outq, loss.
__global__ __launch_bounds__(256) void vq_gather(const float* __restrict__ X,
                                                 const float* __restrict__ E,
                                                 const float2* __restrict__ pairs,
                                                 float* __restrict__ outq,
                                                 float* __restrict__ loss_partial) {
    __shared__ float wsum[4];
    const int tid   = threadIdx.x;
    const int brow0 = blockIdx.x * BLOCK_ROWS;

    float lsum = 0.0f;
    #pragma unroll
    for (int h = 0; h < 2; ++h) {
        const int r   = h * 32 + (tid >> 3);
        const int c8  = tid & 7;
        const int row = brow0 + r;
        const float2 p0 = pairs[(size_t)row * 2 + 0];
        const float2 p1 = pairs[(size_t)row * 2 + 1];
        // half-0 indices are smaller: strict < keeps first-occurrence min
        const int idx = (p1.x < p0.x) ? __float_as_int(p1.y) : __float_as_int(p0.y);
        const float* eq  = E + (size_t)idx * D_DIM;
        const float* xr  = X + (size_t)row * D_DIM;
        float*       orw = outq + (size_t)row * D_DIM;
        #pragma unroll
        for (int j = 0; j < 8; ++j) {
            int d = c8 * 4 + j * 32;
            float4 q = *reinterpret_cast<const float4*>(eq + d);
            float4 x = *reinterpret_cast<const float4*>(xr + d);
            f32x4 qv = {q.x, q.y, q.z, q.w};
            __builtin_nontemporal_store(qv, reinterpret_cast<f32x4*>(orw + d));
            float dx = q.x - x.x, dy = q.y - x.y, dz = q.z - x.z, dw = q.w - x.w;
            lsum += dx * dx + dy * dy + dz * dz + dw * dw;
        }
    }
    #pragma unroll
    for (int off = 32; off; off >>= 1) lsum += __shfl_xor(lsum, off, 64);
    const int wave = tid >> 6, lane = tid & 63;
    if (lane == 0) wsum[wave] = lsum;
    __syncthreads();
    if (tid == 0)
        loss_partial[blockIdx.x] = wsum[0] + wsum[1] + wsum[2] + wsum[3];
}

// ---------------------------------------------------------------- finalize
// deterministic fold of 512 block partials -> vq_loss scalar
__global__ __launch_bounds__(256) void vq_finalize(const float* __restrict__ partials,
                                                   float* __restrict__ out_loss) {
    __shared__ float s[256];
    int t = threadIdx.x;
    s[t] = partials[t] + partials[t + 256];
    __syncthreads();
    #pragma unroll
    for (int off = 128; off; off >>= 1) {
        if (t < off) s[t] += s[t + off];
        __syncthreads();
    }
    if (t == 0)
        out_loss[0] = s[0] * (1.25f / (float)((size_t)N_ROWS * D_DIM));
}

// ---------------------------------------------------------------- launch
extern "C" void kernel_launch(void* const* d_in, const int* in_sizes, int n_in,
                              void* d_out, int out_size, void* d_ws, size_t ws_size,
                              hipStream_t stream) {
    const float* X = (const float*)d_in[0];   // latents  [32768, 256] f32
    const float* E = (const float*)d_in[1];   // codebook [1024, 256]  f32
    float* out = (float*)d_out;               // 8388608 quantized + 1 loss

    float*  enorm    = (float*)d_ws;                      // 1024 f32
    float*  lpart    = enorm + K_CODES;                   // 512 f32 (1024 slot)
    short*  Eb       = (short*)(lpart + 1024);            // 512 KB bf16
    float2* pairs    = (float2*)(Eb + 32768 * 8);         // 32768 x 2 x 8B

    vq_prep    <<<256,  256, 0, stream>>>(E, enorm, Eb);
    vq_main    <<<NBLK, 256, 0, stream>>>(X, enorm, Eb, pairs);
    vq_gather  <<<NRG,  256, 0, stream>>>(X, E, pairs, out, lpart);
    vq_finalize<<<1,    256, 0, stream>>>(lpart, out + (size_t)N_ROWS * D_DIM);
}